// Round 1
// 387.800 us; speedup vs baseline: 1.1054x; 1.1054x over previous
//
#include <hip/hip_runtime.h>
#include <hip/hip_bf16.h>
#include <math.h>

#define B_ 64
#define T_ 2048
#define D_ 512
#define A_ 128

#define CHUNK  32              // tokens per chunk (64 KB fp32 in LDS)
#define NCHUNK 8               // chunks per block
#define SEG    (CHUNK*NCHUNK)  // 256 tokens per block
#define NBLK   (B_*(T_/SEG))   // 512 blocks

typedef __bf16 bf16x8 __attribute__((ext_vector_type(8)));
typedef float  f32x4  __attribute__((ext_vector_type(4)));

// ---------------- Kernel 0: W1 [512][128] fp32 -> W1T [128][512] bf16 ----------------
__global__ __launch_bounds__(256) void prep_kernel(
    const float* __restrict__ W1, __hip_bfloat16* __restrict__ W1T)
{
    int idx = blockIdx.x * 256 + threadIdx.x;   // 64K elements, grid 256
    int k = idx >> 7;          // 0..511
    int n = idx & 127;         // 0..127
    W1T[n * D_ + k] = __float2bfloat16(W1[idx]);
}

__device__ inline bf16x8 cvt8(float4 a, float4 b) {
    bf16x8 r;
    r[0] = (__bf16)a.x; r[1] = (__bf16)a.y; r[2] = (__bf16)a.z; r[3] = (__bf16)a.w;
    r[4] = (__bf16)b.x; r[5] = (__bf16)b.y; r[6] = (__bf16)b.z; r[7] = (__bf16)b.w;
    return r;
}

__device__ inline float fast_tanh(float v) {
    v = fminf(fmaxf(v, -15.f), 15.f);
    float e = __expf(2.f * v);
    return (e - 1.f) / (e + 1.f);
}

typedef __attribute__((address_space(1))) const void gas_t;
typedef __attribute__((address_space(3))) void las_t;
#define GLOAD_LDS16(g, l) \
    __builtin_amdgcn_global_load_lds((gas_t*)(g), (las_t*)(l), 16, 0, 0)

// ---------------- Kernel 1: fused scores + exp + weighted accumulation ----------------
// One pass over x. Block = 256 threads (4 waves), 256 tokens in 8 chunks of 32.
// Chunk staged fp32 into LDS (double-buffered, global_load_lds w=16, XOR-swizzled source).
// Wave wv computes n-quarter [2wv*16, 2wv*16+32) for BOTH 16-token tiles of the chunk.
// No max-subtraction needed: |s| <= sum|W2| + |b2| <= ~11.4, exp(s) safe in fp32.
__global__ __launch_bounds__(256, 1) void fused_kernel(
    const float* __restrict__ x, const __hip_bfloat16* __restrict__ W1T_,
    const float* __restrict__ b1, const float* __restrict__ W2,
    const float* __restrict__ b2,
    float* __restrict__ pS, float* __restrict__ pmu, float* __restrict__ pm2)
{
    __shared__ __align__(16) float xs[2][CHUNK * D_];   // 2 x 64 KB
    __shared__ float parr[4][2][16];
    __shared__ float uarr[CHUNK];

    const __bf16* W1T = (const __bf16*)W1T_;
    const int tid  = threadIdx.x;
    const int wv   = tid >> 6;
    const int lane = tid & 63;
    const int col  = lane & 15;
    const int kgrp = lane >> 4;

    const int bk  = blockIdx.x;
    const int b   = bk >> 3;
    const int seg = bk & 7;
    const float* xb = x + ((long)b * T_ + (long)seg * SEG) * D_;

    // ---- preload W1T fragments for this wave's n-quarter (stays in 128 VGPRs) ----
    bf16x8 af[2][16];
#pragma unroll
    for (int mtl = 0; mtl < 2; mtl++) {
        const __bf16* wp = W1T + (long)((2*wv + mtl)*16 + col) * D_ + kgrp*8;
#pragma unroll
        for (int ks = 0; ks < 16; ks++)
            af[mtl][ks] = *(const bf16x8*)(wp + ks*32);
    }
    float b1v[2][4], w2v[2][4];
#pragma unroll
    for (int mtl = 0; mtl < 2; mtl++)
#pragma unroll
        for (int r = 0; r < 4; r++) {
            int n = (2*wv + mtl)*16 + kgrp*4 + r;
            b1v[mtl][r] = b1[n];
            w2v[mtl][r] = W2[n];
        }
    const float bias2 = b2[0];

    float mu0 = 0.f, mu1 = 0.f, m20 = 0.f, m21 = 0.f, su = 0.f;

    // stage chunk c into xs[bufi]; LDS dest linear, global source XOR-pre-swizzled
    // (granule g of row t holds global granule g^(t&7); 16B granules, 128/row)
    auto STAGE = [&](int bufi, int c) {
        const float* src = xb + (long)c * (CHUNK * D_);
        float* dstbase = &xs[bufi][0];
#pragma unroll
        for (int j = 0; j < 16; j++) {
            int G = j*256 + tid;         // granule 0..4095
            int t = G >> 7;              // token row 0..31
            int g = G & 127;
            const float* gp = src + t*D_ + ((g ^ (t & 7)) << 2);
            float* lp = dstbase + ((j*256 + wv*64) << 2);   // wave-uniform base
            GLOAD_LDS16(gp, lp);
        }
    };

    STAGE(0, 0);
    int cur = 0;

    for (int c = 0; c < NCHUNK; c++) {
        if (c + 1 < NCHUNK) {
            STAGE(cur ^ 1, c + 1);                              // prefetch next chunk
            asm volatile("s_waitcnt vmcnt(16)" ::: "memory");   // only current chunk drained
        } else {
            asm volatile("s_waitcnt vmcnt(0)" ::: "memory");
        }
        __builtin_amdgcn_s_barrier();                           // B1: xs[cur] ready
        asm volatile("" ::: "memory");

        const float* bufp = &xs[cur][0];

        // ---- MFMA: scores for the 32 tokens of this chunk ----
        f32x4 acc[2][2];
#pragma unroll
        for (int mtl = 0; mtl < 2; mtl++)
#pragma unroll
            for (int tt = 0; tt < 2; tt++)
                acc[mtl][tt] = (f32x4){0.f, 0.f, 0.f, 0.f};

#pragma unroll
        for (int ks = 0; ks < 16; ks++) {
            bf16x8 bfr[2];
#pragma unroll
            for (int tt = 0; tt < 2; tt++) {
                int t  = tt*16 + col;
                int m  = t & 7;
                int gb = ks*8 + kgrp*2;
                float4 aa = *(const float4*)(bufp + (t << 9) + (((gb    ) ^ m) << 2));
                float4 bb = *(const float4*)(bufp + (t << 9) + (((gb + 1) ^ m) << 2));
                bfr[tt] = cvt8(aa, bb);
            }
#pragma unroll
            for (int mtl = 0; mtl < 2; mtl++) {
                acc[mtl][0] = __builtin_amdgcn_mfma_f32_16x16x32_bf16(af[mtl][ks], bfr[0], acc[mtl][0], 0, 0, 0);
                acc[mtl][1] = __builtin_amdgcn_mfma_f32_16x16x32_bf16(af[mtl][ks], bfr[1], acc[mtl][1], 0, 0, 0);
            }
        }

        // ---- epilogue: per-wave partial scores (sum over this wave's 32 n's) ----
        float p0 = 0.f, p1 = 0.f;
#pragma unroll
        for (int mtl = 0; mtl < 2; mtl++)
#pragma unroll
            for (int r = 0; r < 4; r++) {
                p0 += fast_tanh(acc[mtl][0][r] + b1v[mtl][r]) * w2v[mtl][r];
                p1 += fast_tanh(acc[mtl][1][r] + b1v[mtl][r]) * w2v[mtl][r];
            }
        p0 += __shfl_xor(p0, 16, 64);
        p0 += __shfl_xor(p0, 32, 64);
        p1 += __shfl_xor(p1, 16, 64);
        p1 += __shfl_xor(p1, 32, 64);
        if (lane < 16) {
            parr[wv][0][lane] = p0;
            parr[wv][1][lane] = p1;
        }
        asm volatile("s_waitcnt lgkmcnt(0)" ::: "memory");
        __builtin_amdgcn_s_barrier();                           // B2: parr visible
        asm volatile("" ::: "memory");

        if (tid < CHUNK) {
            int tt = tid >> 4, cc = tid & 15;
            float s = parr[0][tt][cc] + parr[1][tt][cc]
                    + parr[2][tt][cc] + parr[3][tt][cc] + bias2;
            uarr[tid] = __expf(s);                               // unnormalized weight
        }
        asm volatile("s_waitcnt lgkmcnt(0)" ::: "memory");
        __builtin_amdgcn_s_barrier();                           // B3: uarr visible
        asm volatile("" ::: "memory");

        // ---- weighted accumulation: thread owns d = {2*tid, 2*tid+1} ----
        const int gacc = tid >> 1;            // d-granule 0..127
        const int fo   = (tid & 1) << 1;      // float offset in granule
#pragma unroll
        for (int t = 0; t < CHUNK; t++) {
            float u = uarr[t];
            const float* pp = bufp + (t << 9) + ((gacc ^ (t & 7)) << 2) + fo;
            float2 xv = *(const float2*)pp;
            mu0 = fmaf(u, xv.x, mu0);
            mu1 = fmaf(u, xv.y, mu1);
            m20 = fmaf(u * xv.x, xv.x, m20);
            m21 = fmaf(u * xv.y, xv.y, m21);
            su += u;                          // every thread sums all u (identical)
        }
        asm volatile("" ::: "memory");
        __builtin_amdgcn_s_barrier();                           // B4: reads done, buffer reusable
        asm volatile("" ::: "memory");

        cur ^= 1;
    }

    const int d0 = tid * 2;
    pmu[(long)bk * D_ + d0]     = mu0;
    pmu[(long)bk * D_ + d0 + 1] = mu1;
    pm2[(long)bk * D_ + d0]     = m20;
    pm2[(long)bk * D_ + d0 + 1] = m21;
    if (tid == 0) pS[bk] = su;
}

// ---------------- Kernel 2: merge partials, normalize, finalize ----------------
__global__ __launch_bounds__(256) void merge_kernel(
    const float* __restrict__ pS, const float* __restrict__ pmu,
    const float* __restrict__ pm2, float* __restrict__ out)
{
    const int b = blockIdx.x, tid = threadIdx.x;
    float S = 0.f;
#pragma unroll
    for (int c = 0; c < 8; c++) S += pS[b*8 + c];
    const float inv = 1.f / S;

    const int d0 = tid * 2;
    float mu0 = 0.f, mu1 = 0.f, m20 = 0.f, m21 = 0.f;
#pragma unroll
    for (int c = 0; c < 8; c++) {
        const float* pb = pmu + (long)(b*8 + c) * D_ + d0;
        const float* qb = pm2 + (long)(b*8 + c) * D_ + d0;
        mu0 += pb[0]; mu1 += pb[1];
        m20 += qb[0]; m21 += qb[1];
    }
    mu0 *= inv; mu1 *= inv; m20 *= inv; m21 *= inv;

    float* ob = out + (long)b * (2 * D_);
    ob[d0]     = mu0;
    ob[d0 + 1] = mu1;
    ob[D_ + d0]     = sqrtf(fmaxf(m20 - mu0 * mu0, 0.f) + 1e-6f);
    ob[D_ + d0 + 1] = sqrtf(fmaxf(m21 - mu1 * mu1, 0.f) + 1e-6f);
}

extern "C" void kernel_launch(void* const* d_in, const int* in_sizes, int n_in,
                              void* d_out, int out_size, void* d_ws, size_t ws_size,
                              hipStream_t stream) {
    const float* x  = (const float*)d_in[0];
    const float* W1 = (const float*)d_in[1];
    const float* b1 = (const float*)d_in[2];
    const float* W2 = (const float*)d_in[3];
    const float* b2 = (const float*)d_in[4];
    float* out = (float*)d_out;

    float* ws = (float*)d_ws;
    float* pS  = ws;                                   // 512 f
    float* pmu = ws + 512;                             // 512*512 f
    float* pm2 = pmu + 512L * D_;                      // 512*512 f
    __hip_bfloat16* W1T = (__hip_bfloat16*)(pm2 + 512L * D_);  // 65536 bf16

    prep_kernel<<<256, 256, 0, stream>>>(W1, W1T);
    fused_kernel<<<NBLK, 256, 0, stream>>>(x, W1T, b1, W2, b2, pS, pmu, pm2);
    merge_kernel<<<B_, 256, 0, stream>>>(pS, pmu, pm2, out);
}